// Round 7
// baseline (218.189 us; speedup 1.0000x reference)
//
#include <hip/hip_runtime.h>
#include <hip/hip_bf16.h>
#include <stdint.h>

typedef __bf16 bf16;
typedef __bf16 bf16x8 __attribute__((ext_vector_type(8)));
typedef __bf16 bf16x4 __attribute__((ext_vector_type(4)));
typedef float  f32x4  __attribute__((ext_vector_type(4)));
typedef float  f32x16 __attribute__((ext_vector_type(16)));

#define S_LEN  2048
#define NH     16
#define DKV    64
#define DMODEL 1024
#define LOG2E  1.4426950408889634f

#define SBAR()       __builtin_amdgcn_s_barrier()
#define SFENCE()     __builtin_amdgcn_sched_barrier(0)
#define WAIT_VM(N)   asm volatile("s_waitcnt vmcnt(" #N ")" ::: "memory")
#define WAIT_LGKM0() asm volatile("s_waitcnt lgkmcnt(0)" ::: "memory")

// ---------------------------------------------------------------------------
// async global->LDS 16B copy. LDS dest is wave-uniform base + lane*16.
// ---------------------------------------------------------------------------
__device__ __forceinline__ void async_load16(const void* g, void* l) {
  __builtin_amdgcn_global_load_lds(
      (const __attribute__((address_space(1))) uint32_t*)(uintptr_t)g,
      (__attribute__((address_space(3))) uint32_t*)(uintptr_t)l,
      16, 0, 0);
}

// ---------------------------------------------------------------------------
// prep: z<4 -> transpose-cast W [K][N] fp32 -> bf16 [N][K] (64x64 tiles);
//       z>=4 -> elementwise cast Q/K/V fp32 -> bf16 (f32x4 in, bf16x8 out).
// grid (64,16,7), block 256. Transpose z uses only x<16.
// ---------------------------------------------------------------------------
__global__ void prep(const float* __restrict__ W0, const float* __restrict__ W1,
                     const float* __restrict__ W2, const float* __restrict__ W3,
                     const float* __restrict__ Aq, const float* __restrict__ Ak,
                     const float* __restrict__ Av,
                     bf16* __restrict__ T0, bf16* __restrict__ T1,
                     bf16* __restrict__ T2, bf16* __restrict__ T3,
                     bf16* __restrict__ Qb, bf16* __restrict__ Kb, bf16* __restrict__ Vb)
{
  const int z = blockIdx.z;
  const int tid = threadIdx.x;
  if (z < 4) {
    if (blockIdx.x >= 16) return;        // transpose uses 16x16 blocks
    const float* W = (z == 0) ? W0 : (z == 1) ? W1 : (z == 2) ? W2 : W3;
    bf16* T = (z == 0) ? T0 : (z == 1) ? T1 : (z == 2) ? T2 : T3;
    __shared__ float tile[64][65];
    int n0 = blockIdx.x * 64, k0 = blockIdx.y * 64;
    int c4 = (tid & 15) * 4;
    int rr = tid >> 4;
    for (int g = 0; g < 4; ++g) {
      int k = g * 16 + rr;
      f32x4 v = *(const f32x4*)(W + (size_t)(k0 + k) * DMODEL + n0 + c4);
      tile[k][c4] = v[0]; tile[k][c4 + 1] = v[1];
      tile[k][c4 + 2] = v[2]; tile[k][c4 + 3] = v[3];
    }
    __syncthreads();
    int kc = tid & 7, rn2 = tid >> 3;
    for (int pass = 0; pass < 2; ++pass) {
      int rn = pass * 32 + rn2;
      bf16x8 o;
      for (int w = 0; w < 8; ++w) o[w] = (bf16)tile[kc * 8 + w][rn];
      *(bf16x8*)(T + (size_t)(n0 + rn) * DMODEL + k0 + kc * 8) = o;
    }
  } else {
    const float* S = (z == 4) ? Aq : (z == 5) ? Ak : Av;
    bf16* D = (z == 4) ? Qb : (z == 5) ? Kb : Vb;
    size_t base = (((size_t)blockIdx.y * 64 + blockIdx.x) * 256 + tid) * 16;
    f32x4 v0 = *(const f32x4*)(S + base);
    f32x4 v1 = *(const f32x4*)(S + base + 4);
    f32x4 v2 = *(const f32x4*)(S + base + 8);
    f32x4 v3 = *(const f32x4*)(S + base + 12);
    bf16x8 o0, o1;
    for (int w = 0; w < 4; ++w) { o0[w] = (bf16)v0[w]; o0[w + 4] = (bf16)v1[w]; }
    for (int w = 0; w < 4; ++w) { o1[w] = (bf16)v2[w]; o1[w + 4] = (bf16)v3[w]; }
    *(bf16x8*)(D + base) = o0;
    *(bf16x8*)(D + base + 8) = o1;
  }
}

// ---------------------------------------------------------------------------
// QKV GEMM v3: m97 structure. Pure bf16; A AND B staged via global_load_lds
// (8 DMAs/thread/iter, XOR-pre-swizzled source addresses, linear LDS dest);
// single-buffered 32KB LDS; full vmcnt(0) drain + barrier per K-step.
// No cvt VALU, no register prefetch. Guide-measured regime: 874-912 TF.
// 128x128 tile, BK=64. grid (m=32, n=8, z=3) = 768 = 3/CU (LDS 33.8KB -> 4/CU
// capacity, no dispatch tail). z==2 writes vperm [bh][tile][p][d][8].
// ---------------------------------------------------------------------------
__global__ __launch_bounds__(256) void gemm_qkv(
    const bf16* __restrict__ Aq, const bf16* __restrict__ Ak, const bf16* __restrict__ Av,
    const bf16* __restrict__ Bq, const bf16* __restrict__ Bk, const bf16* __restrict__ Bv,
    bf16* __restrict__ Cq, bf16* __restrict__ Ck, bf16* __restrict__ Cv)
{
  __shared__ __align__(16) char smem[33792];   // As 16K + Bs 16K; Ls overlay 33.8K
  bf16* As = (bf16*)smem;
  bf16* Bs = (bf16*)(smem + 16384);
  bf16* Ls = (bf16*)smem;                // epilogue overlay [128][132]

  const int z = blockIdx.z;
  const bf16* A  = (z == 0) ? Aq : (z == 1) ? Ak : Av;
  const bf16* Bt = (z == 0) ? Bq : (z == 1) ? Bk : Bv;
  bf16* C        = (z == 0) ? Cq : (z == 1) ? Ck : Cv;

  const int m0 = blockIdx.x * 128;       // m on x: XCD-local A reuse
  const int n0 = blockIdx.y * 128;
  const int tid = threadIdx.x;
  const int lane = tid & 63;
  const int wave = tid >> 6;
  const int wm = (wave >> 1) * 64;       // wave output: 64x64
  const int wn = (wave & 1) * 64;
  const int row = lane & 15;
  const int quad = lane >> 4;

  f32x4 acc[4][4];
  for (int i = 0; i < 4; ++i)
    for (int j = 0; j < 4; ++j) acc[i][j] = (f32x4){0.f, 0.f, 0.f, 0.f};

  for (int kt = 0; kt < 16; ++kt) {
    const int kk = kt << 6;
    // stage A(kt) + B(kt): 8 async 16B DMAs per thread, swizzle in src addr
    for (int j = 0; j < 4; ++j) {
      int base = j * 256 + wave * 64;
      int idx = base + lane;
      int r = idx >> 3;
      int cc = (idx & 7) ^ (r & 7);
      async_load16(A  + (size_t)(m0 + r) * DMODEL + kk + cc * 8,
                   (char*)As + (size_t)base * 16);
      async_load16(Bt + (size_t)(n0 + r) * DMODEL + kk + cc * 8,
                   (char*)Bs + (size_t)base * 16);
    }
    WAIT_VM(0);                          // m97-style drain: tile landed
    SBAR();                              // publish
    for (int ks = 0; ks < 2; ++ks) {
      bf16x8 af[4], bfr[4];
      for (int i = 0; i < 4; ++i) {
        int rr = wm + i * 16 + row;
        af[i] = *(const bf16x8*)(As + rr * 64 + (((quad + ks * 4) ^ (rr & 7)) << 3));
      }
      for (int j = 0; j < 4; ++j) {
        int rr = wn + j * 16 + row;
        bfr[j] = *(const bf16x8*)(Bs + rr * 64 + (((quad + ks * 4) ^ (rr & 7)) << 3));
      }
      for (int i = 0; i < 4; ++i)
        for (int j = 0; j < 4; ++j)
          acc[i][j] = __builtin_amdgcn_mfma_f32_16x16x32_bf16(af[i], bfr[j], acc[i][j], 0, 0, 0);
    }
    SBAR();                              // readers done before next stage
  }

  if (z != 2) {
    const int bq = m0 >> 11;
    __syncthreads();
    for (int i = 0; i < 4; ++i)
      for (int j = 0; j < 4; ++j)
        for (int r = 0; r < 4; ++r)
          Ls[(wm + i * 16 + quad * 4 + r) * 132 + wn + j * 16 + row] = (bf16)acc[i][j][r];
    __syncthreads();
    for (int u = 0; u < 8; ++u) {
      int cc = u * 256 + tid;
      int rloc = cc >> 4, c8 = (cc & 15) * 8;
      int s = (m0 + rloc) & 2047;
      int gn = n0 + c8;
      int h = gn >> 6, d = gn & 63;
      bf16x8 val = *(const bf16x8*)(Ls + rloc * 132 + c8);
      *(bf16x8*)(C + (((size_t)(bq * NH + h)) * S_LEN + s) * DKV + d) = val;
    }
  } else {
    // V permuted for attn PV: [bh][tile=s/64][p][d][slot(8)]
    for (int i = 0; i < 4; ++i)
      for (int j = 0; j < 4; ++j) {
        int gm = m0 + wm + i * 16 + quad * 4;
        int gn = n0 + wn + j * 16 + row;
        int b = gm >> 11, s = gm & 2047;
        int h = gn >> 6,  d = gn & 63;
        int bh = b * NH + h;
        int tile = s >> 6, kb = (s & 63) >> 2;
        int half = (kb >> 1) & 1;
        int p = (kb & 1) + ((kb >> 2) & 1) * 2 + (kb >> 3) * 4;
        bf16x4 t;
        for (int r = 0; r < 4; ++r) t[r] = (bf16)acc[i][j][r];
        *(bf16x4*)(C + ((((size_t)bh * 32 + tile) * 8 + p) * 64 + d) * 8 + half * 4) = t;
      }
  }
}

// ---------------------------------------------------------------------------
// Flash attention (round-6 v4) + T5 setprio around MFMA clusters.
// grid (bh=32, q=16, zh=2); LDS 33KB.
// ---------------------------------------------------------------------------
__global__ __launch_bounds__(256, 4) void attn_kernel(
    const bf16* __restrict__ Qh, const bf16* __restrict__ Kh, const bf16* __restrict__ Vperm,
    const float* __restrict__ mask, bf16* __restrict__ Opart, float* __restrict__ Lpart)
{
  __shared__ __align__(16) bf16 Ks[2][64 * 64];
  __shared__ __align__(16) bf16 Vts[2][64 * 64];
  __shared__ __align__(16) float masks2[2][64];

  const int bh = blockIdx.x;
  const int b = bh >> 4;
  const int q0 = blockIdx.y * 128;
  const int zh = blockIdx.z;
  const int tid = threadIdx.x;
  const int lane = tid & 63;
  const int wave = tid >> 6;
  const int ln = lane & 31;
  const int hi = lane >> 5;
  const float SC2 = 0.125f * LOG2E;

  const int qg = q0 + wave * 32 + ln;
  bf16x8 qf[4];
  {
    const bf16* qrow = Qh + ((size_t)bh * S_LEN + qg) * DKV;
    for (int c = 0; c < 4; ++c)
      qf[c] = *(const bf16x8*)(qrow + c * 16 + hi * 8);
  }

  auto stage = [&](int it, int buf) {
    const int kv0 = zh * 1024 + it * 64;
    float mval = 0.f;
    if (tid < 64) mval = mask[b * S_LEN + kv0 + tid];   // issued first
    const bf16* vtile = Vperm + ((size_t)bh * 32 + (kv0 >> 6)) * 4096;
    for (int j = 0; j < 2; ++j) {
      int base = j * 256 + wave * 64;
      int idx = base + lane;
      int r = idx >> 3;
      int cc = (idx & 7) ^ (r & 7);
      async_load16(Kh + ((size_t)bh * S_LEN + kv0 + r) * DKV + cc * 8,
                   (char*)Ks[buf] + (size_t)base * 16);
      async_load16(vtile + (size_t)idx * 8,
                   (char*)Vts[buf] + (size_t)base * 16);
    }
    if (tid < 64) masks2[buf][tid] = mval * LOG2E;
  };

  f32x16 O[2];
  for (int nb = 0; nb < 2; ++nb)
    for (int i = 0; i < 16; ++i) O[nb][i] = 0.f;
  float lsum = 0.f;

  stage(0, 0);                                  // prologue

  for (int it = 0; it < 16; ++it) {
    const int cur = it & 1;
    if (it < 15) stage(it + 1, cur ^ 1);
    SFENCE();
    if (it < 15) { WAIT_VM(4); }                // KV(it) landed; KV(it+1) in flight
    else         { WAIT_VM(0); }
    WAIT_LGKM0();
    SBAR();
    SFENCE();

    // S^T = K * Q^T
    f32x16 Sm[2];
    for (int i = 0; i < 16; ++i) { Sm[0][i] = 0.f; Sm[1][i] = 0.f; }
    __builtin_amdgcn_s_setprio(1);
    for (int c = 0; c < 4; ++c) {
      bf16x8 k0 = *(const bf16x8*)(Ks[cur] + ln * 64        + (((2 * c + hi) ^ (ln & 7)) << 3));
      bf16x8 k1 = *(const bf16x8*)(Ks[cur] + (32 + ln) * 64 + (((2 * c + hi) ^ (ln & 7)) << 3));
      Sm[0] = __builtin_amdgcn_mfma_f32_32x32x16_bf16(k0, qf[c], Sm[0], 0, 0, 0);
      Sm[1] = __builtin_amdgcn_mfma_f32_32x32x16_bf16(k1, qf[c], Sm[1], 0, 0, 0);
    }
    __builtin_amdgcn_s_setprio(0);

    // P = exp2(S*SC2 + mask*LOG2E) -> PV (one b128 per fragment)
    for (int cg = 0; cg < 4; ++cg) {
      int mb = cg >> 1, g = cg & 1;
      int koff = 32 * mb + 16 * g + 4 * hi;
      f32x4 mklo = *(const f32x4*)(&masks2[cur][koff]);
      f32x4 mkhi = *(const f32x4*)(&masks2[cur][koff + 8]);
      bf16x8 ap;
      float ls0 = 0.f;
      for (int u = 0; u < 4; ++u) {
        float p = __builtin_amdgcn_exp2f(Sm[mb][g * 8 + u] * SC2 + mklo[u]);
        ls0 += p; ap[u] = (bf16)p;
      }
      for (int u = 0; u < 4; ++u) {
        float p = __builtin_amdgcn_exp2f(Sm[mb][g * 8 + 4 + u] * SC2 + mkhi[u]);
        ls0 += p; ap[4 + u] = (bf16)p;
      }
      lsum += ls0;
      int p = hi + 2 * g + 4 * mb;
      __builtin_amdgcn_s_setprio(1);
      for (int nb = 0; nb < 2; ++nb) {
        int d = nb * 32 + ln;
        bf16x8 bv = *(const bf16x8*)(Vts[cur] + ((size_t)p * 64 + d) * 8);
        O[nb] = __builtin_amdgcn_mfma_f32_32x32x16_bf16(ap, bv, O[nb], 0, 0, 0);
      }
      __builtin_amdgcn_s_setprio(0);
    }
    SFENCE();
    SBAR();
  }

  float lt = lsum + __shfl_xor(lsum, 32, 64);
  if (lane < 32)
    Lpart[((size_t)zh * 32 + bh) * S_LEN + q0 + wave * 32 + ln] = lt;

  bf16* ob = Opart + (((size_t)zh * 32 + bh) * S_LEN) * DKV;
  for (int g = 0; g < 4; ++g)
    for (int nb = 0; nb < 2; ++nb)
      for (int j = 0; j < 4; ++j) {
        int qrow = q0 + wave * 32 + j + 8 * g + 4 * hi;
        ob[(size_t)qrow * DKV + nb * 32 + ln] = (bf16)O[nb][g * 4 + j];
      }
}

// ---------------------------------------------------------------------------
// Out-GEMM v2 (round-6, unchanged): 64x128 tile; fused combine+normalize on A;
// depth-1 Opart reg prefetch; B dbuf + counted vmcnt.
// grid (m=64, n=8) = 512 blocks; LDS 45KB.
// ---------------------------------------------------------------------------
__global__ __launch_bounds__(256) void gemm_out(
    const bf16* __restrict__ Opart, const float* __restrict__ Lpart,
    const bf16* __restrict__ Wot, float* __restrict__ Cout)
{
  __shared__ __align__(16) bf16 As[64 * 64];
  __shared__ __align__(16) bf16 Bs[2][128 * 64];
  __shared__ float rinv[NH * 64];

  const int m0 = blockIdx.x * 64;
  const int n0 = blockIdx.y * 128;
  const int tid = threadIdx.x;
  const int lane = tid & 63;
  const int wave = tid >> 6;
  const int wm = (wave >> 1) * 32;
  const int wn = (wave & 1) * 64;
  const int row = lane & 15;
  const int quad = lane >> 4;
  const int b = m0 >> 11;
  const int s0 = m0 & 2047;

  for (int u = 0; u < 4; ++u) {
    int idx = u * 256 + tid;
    int h = idx >> 6, r = idx & 63;
    float l = Lpart[(size_t)(b * NH + h) * S_LEN + s0 + r]
            + Lpart[(size_t)(32 + b * NH + h) * S_LEN + s0 + r];
    rinv[idx] = 1.0f / l;
  }
  SFENCE();

  f32x4 acc[2][4];
  for (int i = 0; i < 2; ++i)
    for (int j = 0; j < 4; ++j) acc[i][j] = (f32x4){0.f, 0.f, 0.f, 0.f};

  const int arc = tid & 7;
  const int arr = tid >> 3;
  const size_t HSTEP = (size_t)S_LEN * DKV;
  const size_t ZSTEP = (size_t)32 * S_LEN * DKV;
  const bf16* Oa = Opart + ((size_t)(b * NH) * S_LEN + s0 + arr) * DKV + arc * 8;
  const bf16* Ob = Oa + (size_t)32 * DKV;

  auto stageB = [&](int kt, int buf) {
    for (int j = 0; j < 4; ++j) {
      int base = j * 256 + wave * 64;
      int idx = base + lane;
      int r = idx >> 3;
      int cc = (idx & 7) ^ (r & 7);
      async_load16(Wot + (size_t)(n0 + r) * DMODEL + kt * 64 + cc * 8,
                   (char*)Bs[buf] + (size_t)base * 16);
    }
  };

  bf16x8 h00 = *(const bf16x8*)(Oa);
  bf16x8 h01 = *(const bf16x8*)(Oa + ZSTEP);
  bf16x8 h10 = *(const bf16x8*)(Ob);
  bf16x8 h11 = *(const bf16x8*)(Ob + ZSTEP);
  SFENCE();
  stageB(0, 0);
  SFENCE();
  WAIT_LGKM0();
  SBAR();

  for (int kt = 0; kt < 16; ++kt) {
    const int cur = kt & 1;
    if (kt < 15) stageB(kt + 1, cur ^ 1);
    {
      float rv  = rinv[kt * 64 + arr];
      float rv2 = rinv[kt * 64 + 32 + arr];
      bf16x8 o;
      for (int w = 0; w < 8; ++w)
        o[w] = (bf16)(((float)h00[w] + (float)h01[w]) * rv);
      *(bf16x8*)(As + arr * 64 + ((arc ^ (arr & 7)) << 3)) = o;
      for (int w = 0; w < 8; ++w)
        o[w] = (bf16)(((float)h10[w] + (float)h11[w]) * rv2);
      *(bf16x8*)(As + (32 + arr) * 64 + ((arc ^ (arr & 7)) << 3)) = o;
    }
    if (kt < 15) {
      const size_t off = (size_t)(kt + 1) * HSTEP;
      h00 = *(const bf16x8*)(Oa + off);
      h01 = *(const bf16x8*)(Oa + off + ZSTEP);
      h10 = *(const bf16x8*)(Ob + off);
      h11 = *(const bf16x8*)(Ob + off + ZSTEP);
    }
    SFENCE();
    if (kt < 15) { WAIT_VM(8); }
    else         { WAIT_VM(0); }
    WAIT_LGKM0();
    SBAR();
    SFENCE();
    for (int ks = 0; ks < 2; ++ks) {
      bf16x8 af[2], bfr[4];
      for (int i = 0; i < 2; ++i) {
        int rr = wm + i * 16 + row;
        af[i] = *(const bf16x8*)(As + rr * 64 + (((quad + ks * 4) ^ (rr & 7)) << 3));
      }
      for (int j = 0; j < 4; ++j) {
        int rr = wn + j * 16 + row;
        bfr[j] = *(const bf16x8*)(Bs[cur] + rr * 64 + (((quad + ks * 4) ^ (rr & 7)) << 3));
      }
      for (int i = 0; i < 2; ++i)
        for (int j = 0; j < 4; ++j)
          acc[i][j] = __builtin_amdgcn_mfma_f32_16x16x32_bf16(af[i], bfr[j], acc[i][j], 0, 0, 0);
    }
    SFENCE();
    SBAR();
  }

  for (int i = 0; i < 2; ++i)
    for (int j = 0; j < 4; ++j)
      for (int r = 0; r < 4; ++r) {
        int gm = m0 + wm + i * 16 + quad * 4 + r;
        int gn = n0 + wn + j * 16 + row;
        Cout[(size_t)gm * DMODEL + gn] = acc[i][j][r];
      }
}

// ---------------------------------------------------------------------------
extern "C" void kernel_launch(void* const* d_in, const int* in_sizes, int n_in,
                              void* d_out, int out_size, void* d_ws, size_t ws_size,
                              hipStream_t stream)
{
  const float* query = (const float*)d_in[0];
  const float* key_  = (const float*)d_in[1];
  const float* value = (const float*)d_in[2];
  const float* mask  = (const float*)d_in[3];
  const float* Wq = (const float*)d_in[4];
  const float* Wk = (const float*)d_in[5];
  const float* Wv = (const float*)d_in[6];
  const float* Wo = (const float*)d_in[7];

  char* ws = (char*)d_ws;
  const size_t MB = (size_t)1 << 20;
  bf16* qh    = (bf16*)(ws + 0 * MB);    // 8MB [B,NH,S,DKV]
  bf16* kh    = (bf16*)(ws + 8 * MB);    // 8MB [B,NH,S,DKV]
  bf16* vperm = (bf16*)(ws + 16 * MB);   // 8MB PV-permuted V
  bf16* wot   = (bf16*)(ws + 24 * MB);   // 2MB (live until out-GEMM)
  bf16* Opart = (bf16*)(ws + 26 * MB);   // 16MB bf16 partials (26..42)
  bf16* wqt   = (bf16*)(ws + 26 * MB);   // 2MB each, dead after qkv
  bf16* wkt   = (bf16*)(ws + 28 * MB);
  bf16* wvt   = (bf16*)(ws + 30 * MB);
  bf16* qb    = (bf16*)(ws + 32 * MB);   // 8MB bf16 Q (dead after qkv;
  bf16* kb    = (bf16*)(ws + 40 * MB);   //   overlaps Opart 26..42 by lifetime)
  bf16* vb    = (bf16*)(ws + 48 * MB);   // 8MB (48..56)
  float* Lpart = (float*)(ws + 58 * MB); // 512KB row-sum partials

  prep<<<dim3(64, 16, 7), 256, 0, stream>>>(Wq, Wk, Wv, Wo, query, key_, value,
                                            wqt, wkt, wvt, wot, qb, kb, vb);
  gemm_qkv<<<dim3(32, 8, 3), 256, 0, stream>>>(qb, kb, vb, wqt, wkt, wvt,
                                               qh, kh, vperm);
  attn_kernel<<<dim3(32, 16, 2), 256, 0, stream>>>(qh, kh, vperm, mask, Opart, Lpart);
  gemm_out<<<dim3(64, 8), 256, 0, stream>>>(Opart, Lpart, wot, (float*)d_out);
}

// Round 8
// 209.667 us; speedup vs baseline: 1.0406x; 1.0406x over previous
//
#include <hip/hip_runtime.h>
#include <hip/hip_bf16.h>
#include <stdint.h>

typedef __bf16 bf16;
typedef __bf16 bf16x8 __attribute__((ext_vector_type(8)));
typedef __bf16 bf16x4 __attribute__((ext_vector_type(4)));
typedef float  f32x4  __attribute__((ext_vector_type(4)));
typedef float  f32x16 __attribute__((ext_vector_type(16)));

#define S_LEN  2048
#define NH     16
#define DKV    64
#define DMODEL 1024
#define LOG2E  1.4426950408889634f

#define SBAR()       __builtin_amdgcn_s_barrier()
#define SFENCE()     __builtin_amdgcn_sched_barrier(0)
#define WAIT_VM(N)   asm volatile("s_waitcnt vmcnt(" #N ")" ::: "memory")
#define WAIT_LGKM0() asm volatile("s_waitcnt lgkmcnt(0)" ::: "memory")

// ---------------------------------------------------------------------------
// async global->LDS 16B copy. LDS dest is wave-uniform base + lane*16.
// ---------------------------------------------------------------------------
__device__ __forceinline__ void async_load16(const void* g, void* l) {
  __builtin_amdgcn_global_load_lds(
      (const __attribute__((address_space(1))) uint32_t*)(uintptr_t)g,
      (__attribute__((address_space(3))) uint32_t*)(uintptr_t)l,
      16, 0, 0);
}

// ---------------------------------------------------------------------------
// prep: z<4 -> transpose-cast W [K][N] fp32 -> bf16 [N][K] (64x64 tiles);
//       z>=4 -> elementwise cast Q/K/V fp32 -> bf16 (f32x4 in, bf16x8 out).
// grid (64,16,7), block 256. Transpose z uses only x<16.
// ---------------------------------------------------------------------------
__global__ void prep(const float* __restrict__ W0, const float* __restrict__ W1,
                     const float* __restrict__ W2, const float* __restrict__ W3,
                     const float* __restrict__ Aq, const float* __restrict__ Ak,
                     const float* __restrict__ Av,
                     bf16* __restrict__ T0, bf16* __restrict__ T1,
                     bf16* __restrict__ T2, bf16* __restrict__ T3,
                     bf16* __restrict__ Qb, bf16* __restrict__ Kb, bf16* __restrict__ Vb)
{
  const int z = blockIdx.z;
  const int tid = threadIdx.x;
  if (z < 4) {
    if (blockIdx.x >= 16) return;        // transpose uses 16x16 blocks
    const float* W = (z == 0) ? W0 : (z == 1) ? W1 : (z == 2) ? W2 : W3;
    bf16* T = (z == 0) ? T0 : (z == 1) ? T1 : (z == 2) ? T2 : T3;
    __shared__ float tile[64][65];
    int n0 = blockIdx.x * 64, k0 = blockIdx.y * 64;
    int c4 = (tid & 15) * 4;
    int rr = tid >> 4;
    for (int g = 0; g < 4; ++g) {
      int k = g * 16 + rr;
      f32x4 v = *(const f32x4*)(W + (size_t)(k0 + k) * DMODEL + n0 + c4);
      tile[k][c4] = v[0]; tile[k][c4 + 1] = v[1];
      tile[k][c4 + 2] = v[2]; tile[k][c4 + 3] = v[3];
    }
    __syncthreads();
    int kc = tid & 7, rn2 = tid >> 3;
    for (int pass = 0; pass < 2; ++pass) {
      int rn = pass * 32 + rn2;
      bf16x8 o;
      for (int w = 0; w < 8; ++w) o[w] = (bf16)tile[kc * 8 + w][rn];
      *(bf16x8*)(T + (size_t)(n0 + rn) * DMODEL + k0 + kc * 8) = o;
    }
  } else {
    const float* S = (z == 4) ? Aq : (z == 5) ? Ak : Av;
    bf16* D = (z == 4) ? Qb : (z == 5) ? Kb : Vb;
    size_t base = (((size_t)blockIdx.y * 64 + blockIdx.x) * 256 + tid) * 16;
    f32x4 v0 = *(const f32x4*)(S + base);
    f32x4 v1 = *(const f32x4*)(S + base + 4);
    f32x4 v2 = *(const f32x4*)(S + base + 8);
    f32x4 v3 = *(const f32x4*)(S + base + 12);
    bf16x8 o0, o1;
    for (int w = 0; w < 4; ++w) { o0[w] = (bf16)v0[w]; o0[w + 4] = (bf16)v1[w]; }
    for (int w = 0; w < 4; ++w) { o1[w] = (bf16)v2[w]; o1[w + 4] = (bf16)v3[w]; }
    *(bf16x8*)(D + base) = o0;
    *(bf16x8*)(D + base + 8) = o1;
  }
}

// ---------------------------------------------------------------------------
// QKV GEMM v3 (round-7, unchanged): m97 structure, pure bf16, A+B via
// global_load_lds, single-buffered LDS, vmcnt(0) drain per K-step.
// grid (m=32, n=8, z=3) = 768 = 3/CU; LDS 33.8KB.
// ---------------------------------------------------------------------------
__global__ __launch_bounds__(256) void gemm_qkv(
    const bf16* __restrict__ Aq, const bf16* __restrict__ Ak, const bf16* __restrict__ Av,
    const bf16* __restrict__ Bq, const bf16* __restrict__ Bk, const bf16* __restrict__ Bv,
    bf16* __restrict__ Cq, bf16* __restrict__ Ck, bf16* __restrict__ Cv)
{
  __shared__ __align__(16) char smem[33792];   // As 16K + Bs 16K; Ls overlay 33.8K
  bf16* As = (bf16*)smem;
  bf16* Bs = (bf16*)(smem + 16384);
  bf16* Ls = (bf16*)smem;                // epilogue overlay [128][132]

  const int z = blockIdx.z;
  const bf16* A  = (z == 0) ? Aq : (z == 1) ? Ak : Av;
  const bf16* Bt = (z == 0) ? Bq : (z == 1) ? Bk : Bv;
  bf16* C        = (z == 0) ? Cq : (z == 1) ? Ck : Cv;

  const int m0 = blockIdx.x * 128;       // m on x: XCD-local A reuse
  const int n0 = blockIdx.y * 128;
  const int tid = threadIdx.x;
  const int lane = tid & 63;
  const int wave = tid >> 6;
  const int wm = (wave >> 1) * 64;       // wave output: 64x64
  const int wn = (wave & 1) * 64;
  const int row = lane & 15;
  const int quad = lane >> 4;

  f32x4 acc[4][4];
  for (int i = 0; i < 4; ++i)
    for (int j = 0; j < 4; ++j) acc[i][j] = (f32x4){0.f, 0.f, 0.f, 0.f};

  for (int kt = 0; kt < 16; ++kt) {
    const int kk = kt << 6;
    for (int j = 0; j < 4; ++j) {
      int base = j * 256 + wave * 64;
      int idx = base + lane;
      int r = idx >> 3;
      int cc = (idx & 7) ^ (r & 7);
      async_load16(A  + (size_t)(m0 + r) * DMODEL + kk + cc * 8,
                   (char*)As + (size_t)base * 16);
      async_load16(Bt + (size_t)(n0 + r) * DMODEL + kk + cc * 8,
                   (char*)Bs + (size_t)base * 16);
    }
    WAIT_VM(0);                          // m97-style drain: tile landed
    SBAR();                              // publish
    for (int ks = 0; ks < 2; ++ks) {
      bf16x8 af[4], bfr[4];
      for (int i = 0; i < 4; ++i) {
        int rr = wm + i * 16 + row;
        af[i] = *(const bf16x8*)(As + rr * 64 + (((quad + ks * 4) ^ (rr & 7)) << 3));
      }
      for (int j = 0; j < 4; ++j) {
        int rr = wn + j * 16 + row;
        bfr[j] = *(const bf16x8*)(Bs + rr * 64 + (((quad + ks * 4) ^ (rr & 7)) << 3));
      }
      for (int i = 0; i < 4; ++i)
        for (int j = 0; j < 4; ++j)
          acc[i][j] = __builtin_amdgcn_mfma_f32_16x16x32_bf16(af[i], bfr[j], acc[i][j], 0, 0, 0);
    }
    SBAR();                              // readers done before next stage
  }

  if (z != 2) {
    const int bq = m0 >> 11;
    __syncthreads();
    for (int i = 0; i < 4; ++i)
      for (int j = 0; j < 4; ++j)
        for (int r = 0; r < 4; ++r)
          Ls[(wm + i * 16 + quad * 4 + r) * 132 + wn + j * 16 + row] = (bf16)acc[i][j][r];
    __syncthreads();
    for (int u = 0; u < 8; ++u) {
      int cc = u * 256 + tid;
      int rloc = cc >> 4, c8 = (cc & 15) * 8;
      int s = (m0 + rloc) & 2047;
      int gn = n0 + c8;
      int h = gn >> 6, d = gn & 63;
      bf16x8 val = *(const bf16x8*)(Ls + rloc * 132 + c8);
      *(bf16x8*)(C + (((size_t)(bq * NH + h)) * S_LEN + s) * DKV + d) = val;
    }
  } else {
    // V permuted for attn PV: [bh][tile=s/64][p][d][slot(8)]
    for (int i = 0; i < 4; ++i)
      for (int j = 0; j < 4; ++j) {
        int gm = m0 + wm + i * 16 + quad * 4;
        int gn = n0 + wn + j * 16 + row;
        int b = gm >> 11, s = gm & 2047;
        int h = gn >> 6,  d = gn & 63;
        int bh = b * NH + h;
        int tile = s >> 6, kb = (s & 63) >> 2;
        int half = (kb >> 1) & 1;
        int p = (kb & 1) + ((kb >> 2) & 1) * 2 + (kb >> 3) * 4;
        bf16x4 t;
        for (int r = 0; r < 4; ++r) t[r] = (bf16)acc[i][j][r];
        *(bf16x4*)(C + ((((size_t)bh * 32 + tile) * 8 + p) * 64 + d) * 8 + half * 4) = t;
      }
  }
}

// ---------------------------------------------------------------------------
// Flash attention v5: NO kv-split (32 tiles/block -> full row-sum in-register);
// fused normalize; writes final ctx bf16 [B*S][DMODEL]. setprio REVERTED
// (round-7: +6us on this barrier-locked 4-wave structure, m190 mechanism).
// grid (bh=32, q=16) = 512 blocks = 2/CU; LDS 33.8KB.
// ---------------------------------------------------------------------------
__global__ __launch_bounds__(256, 4) void attn_kernel(
    const bf16* __restrict__ Qh, const bf16* __restrict__ Kh, const bf16* __restrict__ Vperm,
    const float* __restrict__ mask, bf16* __restrict__ ctx)
{
  __shared__ __align__(16) bf16 Ks[2][64 * 64];
  __shared__ __align__(16) bf16 Vts[2][64 * 64];
  __shared__ __align__(16) float masks2[2][64];
  __shared__ float lrow[128];            // per-q-row 1/l exchange

  const int bh = blockIdx.x;
  const int b = bh >> 4;
  const int q0 = blockIdx.y * 128;
  const int tid = threadIdx.x;
  const int lane = tid & 63;
  const int wave = tid >> 6;
  const int ln = lane & 31;
  const int hi = lane >> 5;
  const float SC2 = 0.125f * LOG2E;

  const int qg = q0 + wave * 32 + ln;
  bf16x8 qf[4];
  {
    const bf16* qrow = Qh + ((size_t)bh * S_LEN + qg) * DKV;
    for (int c = 0; c < 4; ++c)
      qf[c] = *(const bf16x8*)(qrow + c * 16 + hi * 8);
  }

  auto stage = [&](int it, int buf) {
    const int kv0 = it * 64;
    float mval = 0.f;
    if (tid < 64) mval = mask[b * S_LEN + kv0 + tid];   // issued first
    const bf16* vtile = Vperm + ((size_t)bh * 32 + it) * 4096;
    for (int j = 0; j < 2; ++j) {
      int base = j * 256 + wave * 64;
      int idx = base + lane;
      int r = idx >> 3;
      int cc = (idx & 7) ^ (r & 7);
      async_load16(Kh + ((size_t)bh * S_LEN + kv0 + r) * DKV + cc * 8,
                   (char*)Ks[buf] + (size_t)base * 16);
      async_load16(vtile + (size_t)idx * 8,
                   (char*)Vts[buf] + (size_t)base * 16);
    }
    if (tid < 64) masks2[buf][tid] = mval * LOG2E;
  };

  f32x16 O[2];
  for (int nb = 0; nb < 2; ++nb)
    for (int i = 0; i < 16; ++i) O[nb][i] = 0.f;
  float lsum = 0.f;

  stage(0, 0);                                  // prologue

  for (int it = 0; it < 32; ++it) {
    const int cur = it & 1;
    if (it < 31) stage(it + 1, cur ^ 1);
    SFENCE();
    if (it < 31) { WAIT_VM(4); }                // KV(it) landed; KV(it+1) in flight
    else         { WAIT_VM(0); }
    WAIT_LGKM0();
    SBAR();
    SFENCE();

    // S^T = K * Q^T
    f32x16 Sm[2];
    for (int i = 0; i < 16; ++i) { Sm[0][i] = 0.f; Sm[1][i] = 0.f; }
    for (int c = 0; c < 4; ++c) {
      bf16x8 k0 = *(const bf16x8*)(Ks[cur] + ln * 64        + (((2 * c + hi) ^ (ln & 7)) << 3));
      bf16x8 k1 = *(const bf16x8*)(Ks[cur] + (32 + ln) * 64 + (((2 * c + hi) ^ (ln & 7)) << 3));
      Sm[0] = __builtin_amdgcn_mfma_f32_32x32x16_bf16(k0, qf[c], Sm[0], 0, 0, 0);
      Sm[1] = __builtin_amdgcn_mfma_f32_32x32x16_bf16(k1, qf[c], Sm[1], 0, 0, 0);
    }

    // P = exp2(S*SC2 + mask*LOG2E) -> PV (one b128 per fragment)
    for (int cg = 0; cg < 4; ++cg) {
      int mb = cg >> 1, g = cg & 1;
      int koff = 32 * mb + 16 * g + 4 * hi;
      f32x4 mklo = *(const f32x4*)(&masks2[cur][koff]);
      f32x4 mkhi = *(const f32x4*)(&masks2[cur][koff + 8]);
      bf16x8 ap;
      float ls0 = 0.f;
      for (int u = 0; u < 4; ++u) {
        float p = __builtin_amdgcn_exp2f(Sm[mb][g * 8 + u] * SC2 + mklo[u]);
        ls0 += p; ap[u] = (bf16)p;
      }
      for (int u = 0; u < 4; ++u) {
        float p = __builtin_amdgcn_exp2f(Sm[mb][g * 8 + 4 + u] * SC2 + mkhi[u]);
        ls0 += p; ap[4 + u] = (bf16)p;
      }
      lsum += ls0;
      int p = hi + 2 * g + 4 * mb;
      for (int nb = 0; nb < 2; ++nb) {
        int d = nb * 32 + ln;
        bf16x8 bv = *(const bf16x8*)(Vts[cur] + ((size_t)p * 64 + d) * 8);
        O[nb] = __builtin_amdgcn_mfma_f32_32x32x16_bf16(ap, bv, O[nb], 0, 0, 0);
      }
    }
    SFENCE();
    SBAR();
  }

  // full row sums (no split): lane ln holds column q = wave*32+ln partial (its
  // hi-half of kv rows); xor-32 combines halves -> full sum.
  float lt = lsum + __shfl_xor(lsum, 32, 64);
  if (hi == 0) lrow[wave * 32 + ln] = 1.0f / lt;
  __syncthreads();

  // normalized ctx write: ctx[b*S + q][h*64 + d]
  const int hcol = (bh & 15) * DKV;
  for (int g = 0; g < 4; ++g)
    for (int j = 0; j < 4; ++j) {
      int qrl = wave * 32 + j + 8 * g + 4 * hi;
      float sc = lrow[qrl];
      for (int nb = 0; nb < 2; ++nb)
        ctx[((size_t)(b * S_LEN + q0 + qrl)) * DMODEL + hcol + nb * 32 + ln]
          = (bf16)(O[nb][g * 4 + j] * sc);
    }
}

// ---------------------------------------------------------------------------
// Out-GEMM v3: pure bf16 GEMM ctx[4096,1024] x wot[1024,1024]^T -> fp32.
// Both operands via global_load_lds; LDS double-buffered; counted vmcnt(6)
// (never 0 mid-loop). 64x128 tile, BK=64; 16 MFMA / 12 b128 per wave-iter.
// grid (m=64, n=8) = 512 blocks = 2/CU; LDS 48KB.
// ---------------------------------------------------------------------------
__global__ __launch_bounds__(256) void gemm_out(
    const bf16* __restrict__ Ctx, const bf16* __restrict__ Wot, float* __restrict__ Cout)
{
  __shared__ __align__(16) bf16 As[2][64 * 64];    // 16KB dbuf
  __shared__ __align__(16) bf16 Bs[2][128 * 64];   // 32KB dbuf

  const int m0 = blockIdx.x * 64;        // m on x: XCD-local ctx reuse
  const int n0 = blockIdx.y * 128;
  const int tid = threadIdx.x;
  const int lane = tid & 63;
  const int wave = tid >> 6;
  const int wm = (wave >> 1) * 32;
  const int wn = (wave & 1) * 64;
  const int row = lane & 15;
  const int quad = lane >> 4;

  f32x4 acc[2][4];
  for (int i = 0; i < 2; ++i)
    for (int j = 0; j < 4; ++j) acc[i][j] = (f32x4){0.f, 0.f, 0.f, 0.f};

  // 6 async ops/thread: A 2 (512 chunks) + B 4 (1024 chunks), swizzled src
  auto stage = [&](int kt, int buf) {
    const int kk = kt << 6;
    for (int j = 0; j < 2; ++j) {
      int base = j * 256 + wave * 64;
      int idx = base + lane;
      int r = idx >> 3;
      int cc = (idx & 7) ^ (r & 7);
      async_load16(Ctx + (size_t)(m0 + r) * DMODEL + kk + cc * 8,
                   (char*)As[buf] + (size_t)base * 16);
    }
    for (int j = 0; j < 4; ++j) {
      int base = j * 256 + wave * 64;
      int idx = base + lane;
      int r = idx >> 3;
      int cc = (idx & 7) ^ (r & 7);
      async_load16(Wot + (size_t)(n0 + r) * DMODEL + kk + cc * 8,
                   (char*)Bs[buf] + (size_t)base * 16);
    }
  };

  stage(0, 0);                           // prologue: tile 0 in flight

  for (int kt = 0; kt < 16; ++kt) {
    const int cur = kt & 1;
    if (kt < 15) stage(kt + 1, cur ^ 1); // other buffer free since end-bar(kt-1)
    SFENCE();
    if (kt < 15) { WAIT_VM(6); }         // tile kt landed; kt+1's 6 in flight
    else         { WAIT_VM(0); }
    SBAR();                              // all waves' tile-kt DMAs landed
    SFENCE();
    for (int ks = 0; ks < 2; ++ks) {
      bf16x8 af[2], bfr[4];
      for (int i = 0; i < 2; ++i) {
        int rr = wm + i * 16 + row;
        af[i] = *(const bf16x8*)(As[cur] + rr * 64 + (((quad + ks * 4) ^ (rr & 7)) << 3));
      }
      for (int j = 0; j < 4; ++j) {
        int rr = wn + j * 16 + row;
        bfr[j] = *(const bf16x8*)(Bs[cur] + rr * 64 + (((quad + ks * 4) ^ (rr & 7)) << 3));
      }
      for (int i = 0; i < 2; ++i)
        for (int j = 0; j < 4; ++j)
          acc[i][j] = __builtin_amdgcn_mfma_f32_16x16x32_bf16(af[i], bfr[j], acc[i][j], 0, 0, 0);
    }
    SFENCE();
    SBAR();                              // readers done before overwrite
  }

  for (int i = 0; i < 2; ++i)
    for (int j = 0; j < 4; ++j)
      for (int r = 0; r < 4; ++r) {
        int gm = m0 + wm + i * 16 + quad * 4 + r;
        int gn = n0 + wn + j * 16 + row;
        Cout[(size_t)gm * DMODEL + gn] = acc[i][j][r];
      }
}

// ---------------------------------------------------------------------------
extern "C" void kernel_launch(void* const* d_in, const int* in_sizes, int n_in,
                              void* d_out, int out_size, void* d_ws, size_t ws_size,
                              hipStream_t stream)
{
  const float* query = (const float*)d_in[0];
  const float* key_  = (const float*)d_in[1];
  const float* value = (const float*)d_in[2];
  const float* mask  = (const float*)d_in[3];
  const float* Wq = (const float*)d_in[4];
  const float* Wk = (const float*)d_in[5];
  const float* Wv = (const float*)d_in[6];
  const float* Wo = (const float*)d_in[7];

  char* ws = (char*)d_ws;
  const size_t MB = (size_t)1 << 20;
  bf16* qh    = (bf16*)(ws + 0 * MB);    // 8MB [B,NH,S,DKV]
  bf16* kh    = (bf16*)(ws + 8 * MB);    // 8MB [B,NH,S,DKV]
  bf16* vperm = (bf16*)(ws + 16 * MB);   // 8MB PV-permuted V
  bf16* wot   = (bf16*)(ws + 24 * MB);   // 2MB (live until out-GEMM)
  bf16* ctx   = (bf16*)(ws + 26 * MB);   // 8MB normalized ctx (26..34)
  bf16* wqt   = (bf16*)(ws + 34 * MB);   // 2MB each (dead after qkv)
  bf16* wkt   = (bf16*)(ws + 36 * MB);
  bf16* wvt   = (bf16*)(ws + 38 * MB);
  bf16* qb    = (bf16*)(ws + 40 * MB);   // 8MB bf16 inputs (dead after qkv)
  bf16* kb    = (bf16*)(ws + 48 * MB);
  bf16* vb    = (bf16*)(ws + 56 * MB);

  prep<<<dim3(64, 16, 7), 256, 0, stream>>>(Wq, Wk, Wv, Wo, query, key_, value,
                                            wqt, wkt, wvt, wot, qb, kb, vb);
  gemm_qkv<<<dim3(32, 8, 3), 256, 0, stream>>>(qb, kb, vb, wqt, wkt, wvt,
                                               qh, kh, vperm);
  attn_kernel<<<dim3(32, 16), 256, 0, stream>>>(qh, kh, vperm, mask, ctx);
  gemm_out<<<dim3(64, 8), 256, 0, stream>>>(ctx, wot, (float*)d_out);
}